// Round 2
// baseline (851.675 us; speedup 1.0000x reference)
//
#include <hip/hip_runtime.h>

#define T_STEPS 512
#define IN_DIM 11
#define ROW_PAD 12                  // x row padded to 12 floats in LDS
#define H_DIM 16
#define ROW_F (T_STEPS * IN_DIM)    // 5632 floats per batch row
#define CHUNK_T 16                  // t-steps per chunk (pipeline granule)
#define CHUNK_F (CHUNK_T * IN_DIM)  // 176 source floats per chunk
#define N_CHUNK (T_STEPS / CHUNK_T)
#define LOG2E 1.44269504088896340736f

typedef float v2f __attribute__((ext_vector_type(2)));
typedef float v4f __attribute__((ext_vector_type(4)));

// Packed fp32 FMA (v_pk_fma_f32): 2 MACs/instr, full rate.
__device__ __forceinline__ v2f pk_fma(v2f a, v2f b, v2f c) {
    v2f d;
    asm("v_pk_fma_f32 %0, %1, %2, %3" : "=v"(d) : "v"(a), "v"(b), "v"(c));
    return d;
}

// DPP quad_perm broadcast within each group of 4 lanes.
template<int CTRL>
__device__ __forceinline__ float qperm(float v) {
    return __builtin_bit_cast(float,
        __builtin_amdgcn_update_dpp(0, __builtin_bit_cast(int, v),
                                    CTRL, 0xf, 0xf, true));
}

__device__ __forceinline__ float bcast_lane(float v, int l) {
    return __builtin_bit_cast(float,
        __builtin_amdgcn_readlane(__builtin_bit_cast(int, v), l));
}

// LAYER-PIPELINED 2-layer LSTM.
// Block = 256 threads = 4 waves = 2 batches x {L1-wave, L2-wave}.
//   wave 0,1: layer-1 for batch bw=0,1  (consumes x, produces h1 ring)
//   wave 2,3: layer-2 for batch bw=0,1  (consumes h1 ring, one chunk behind)
// Rationale (round-1 counters): latency-bound at ~1830 cyc/step with only
// ~11 waves/CU resident (grid-capped). Splitting layers across waves halves
// each wave's serial chain AND doubles wave count (8192 waves = 32/CU),
// flipping the kernel into the issue-bound regime.
// Per-chunk __syncthreads() (33 total) publishes the double-buffered h1 ring.
// Lane = 4*r + gate (i,f,g,o quads); weights M-scaled in pinned VGPRs.
__global__ __launch_bounds__(256, 8) void lstm2_head(
    const float* __restrict__ x,
    const float* __restrict__ Wih1, const float* __restrict__ Whh1,
    const float* __restrict__ bih1, const float* __restrict__ bhh1,
    const float* __restrict__ Wih2, const float* __restrict__ Whh2,
    const float* __restrict__ bih2, const float* __restrict__ bhh2,
    const float* __restrict__ Wd1, const float* __restrict__ bd1,
    const float* __restrict__ Wd2, const float* __restrict__ bd2,
    const float* __restrict__ Wd3, const float* __restrict__ bd3,
    float* __restrict__ out)
{
    __shared__ alignas(16) float xlds[2][212];                 // [bw][padded chunk]
    __shared__ alignas(16) float ring[2][2][CHUNK_T][H_DIM];   // [bw][buf][t2][r]
    __shared__ alignas(16) float shh2[2][H_DIM];               // [bw][r] h2 bcast slab

    const int lane = threadIdx.x & 63;
    const int wid = __builtin_amdgcn_readfirstlane((int)(threadIdx.x >> 6));
    const int isL2 = wid >> 1;          // 0: layer-1 wave, 1: layer-2 wave
    const int bw   = wid & 1;           // batch slot within block
    const int b    = blockIdx.x * 2 + bw;

    const int r   = lane >> 2;          // hidden index 0..15
    const int gt  = lane & 3;           // 0:i 1:f 2:g(tanh) 3:o
    const int row = gt * H_DIM + r;     // row in packed 4H weights

    const bool is_t = (gt == 2);
    const float M   = is_t ? (-2.0f * LOG2E) : (-LOG2E);
    const float vAa = is_t ? 2.0f : 1.0f;
    const float vBc = is_t ? -1.0f : 0.0f;

    // ---- per-wave weights (M-scaled), packed in v2f, pinned ----
    // L1: win = Wih1 (6 pairs used, 11 inputs + zero pad), wrec = Whh1
    // L2: win = Wih2, wrec = Whh2
    v2f win[8], wrec[8];
    float bb;
    if (!isL2) {
        #pragma unroll
        for (int j = 0; j < 5; ++j)
            win[j] = (v2f){M * Wih1[row * IN_DIM + 2 * j],
                           M * Wih1[row * IN_DIM + 2 * j + 1]};
        win[5] = (v2f){M * Wih1[row * IN_DIM + 10], 0.0f};   // pad weight = 0
        win[6] = (v2f){0.f, 0.f};
        win[7] = (v2f){0.f, 0.f};
        #pragma unroll
        for (int j = 0; j < 8; ++j)
            wrec[j] = (v2f){M * Whh1[row * H_DIM + 2 * j],
                            M * Whh1[row * H_DIM + 2 * j + 1]};
        bb = M * (bih1[row] + bhh1[row]);
    } else {
        #pragma unroll
        for (int j = 0; j < 8; ++j) {
            win[j]  = (v2f){M * Wih2[row * H_DIM + 2 * j],
                            M * Wih2[row * H_DIM + 2 * j + 1]};
            wrec[j] = (v2f){M * Whh2[row * H_DIM + 2 * j],
                            M * Whh2[row * H_DIM + 2 * j + 1]};
        }
        bb = M * (bih2[row] + bhh2[row]);
    }
    #pragma unroll
    for (int j = 0; j < 8; ++j) {
        asm volatile("" : "+v"(win[j]));
        asm volatile("" : "+v"(wrec[j]));
    }

    // x staging offsets (L1 waves): source float f -> slot (f/11)*12 + f%11
    const int f1i = lane, f2i = lane + 64, f3i = lane + 128;
    const int p1 = (f1i / IN_DIM) * ROW_PAD + (f1i % IN_DIM);
    const int p2 = (f2i / IN_DIM) * ROW_PAD + (f2i % IN_DIM);
    const int p3 = (f3i / IN_DIM) * ROW_PAD + (f3i % IN_DIM);
    const float* __restrict__ xb = x + (size_t)b * ROW_F;

    float gl0 = 0.f, gl1 = 0.f, gl2 = 0.f;
    if (!isL2) {
        if (lane < 16) xlds[bw][lane * ROW_PAD + IN_DIM] = 0.0f;  // zero pad slots
        gl0 = xb[f1i];                      // prologue: global-load chunk 0
        gl1 = xb[f2i];
        gl2 = xb[min(f3i, ROW_F - 1)];
    }

    float cst = 0.f, ssum = 0.f, h2v = 0.f;
    v2f hr[8];                              // recurrent h pairs (own layer)
    #pragma unroll
    for (int j = 0; j < 8; ++j) hr[j] = (v2f){0.f, 0.f};

    for (int ck = 0; ck <= N_CHUNK; ++ck) {
        __syncthreads();                    // publish ring chunk ck-1 to L2 waves

        if (!isL2) {
            // -------- layer-1 producer: chunk ck -> ring[ck&1] --------
            if (ck < N_CHUNK) {
                float* const xbuf = &xlds[bw][0];
                xbuf[p1] = gl0;
                xbuf[p2] = gl1;
                xbuf[p3] = gl2;
                if (ck + 1 < N_CHUNK) {
                    const int base = (ck + 1) * CHUNK_F;
                    gl0 = xb[base + f1i];
                    gl1 = xb[base + f2i];
                    gl2 = xb[min(base + f3i, ROW_F - 1)];
                }
                float (* const rg)[H_DIM] = ring[bw][ck & 1];
                #pragma unroll
                for (int t2 = 0; t2 < CHUNK_T; ++t2) {
                    const v2f* const xr = (const v2f*)(xbuf + t2 * ROW_PAD);
                    v2f ap = pk_fma(win[0], xr[0], (v2f){bb, 0.f});
                    v2f aq = pk_fma(win[1], xr[1], (v2f){0.f, 0.f});
                    ap = pk_fma(win[2], xr[2], ap);
                    aq = pk_fma(win[3], xr[3], aq);
                    ap = pk_fma(win[4], xr[4], ap);
                    aq = pk_fma(win[5], xr[5], aq);
                    #pragma unroll
                    for (int j = 0; j < 8; j += 2) {
                        ap = pk_fma(wrec[j],     hr[j],     ap);
                        aq = pk_fma(wrec[j + 1], hr[j + 1], aq);
                    }
                    const v2f s = ap + aq;
                    const float g = s.x + s.y;
                    const float a = __builtin_fmaf(vAa,
                        __builtin_amdgcn_rcpf(1.0f + __builtin_amdgcn_exp2f(g)), vBc);
                    const float gi = qperm<0x00>(a);
                    const float gf = qperm<0x55>(a);
                    const float gg = qperm<0xAA>(a);
                    const float go = qperm<0xFF>(a);
                    cst = __builtin_fmaf(gf, cst, gi * gg);
                    const float tc = __builtin_fmaf(2.0f,
                        __builtin_amdgcn_rcpf(1.0f +
                            __builtin_amdgcn_exp2f(-2.0f * LOG2E * cst)), -1.0f);
                    rg[t2][r] = go * tc;            // quad-replicated write
                    // read row back ONCE for next step's recurrent dot
                    const v4f* const hq = (const v4f*)&rg[t2][0];
                    #pragma unroll
                    for (int j = 0; j < 4; ++j) {
                        const v4f q = hq[j];
                        hr[2 * j]     = (v2f){q.x, q.y};
                        hr[2 * j + 1] = (v2f){q.z, q.w};
                    }
                }
            }
        } else {
            // -------- layer-2 consumer: chunk ck-1 <- ring[(ck-1)&1] --------
            if (ck >= 1) {
                float (* const rg)[H_DIM] = ring[bw][(ck - 1) & 1];
                #pragma unroll
                for (int t2 = 0; t2 < CHUNK_T; ++t2) {
                    const v4f* const hq = (const v4f*)&rg[t2][0];
                    // stage first half of h1 row early (overlap with wh2 dot)
                    const v4f q0 = hq[0];
                    const v4f q1 = hq[1];
                    v2f ap = pk_fma(wrec[0], hr[0], (v2f){bb, 0.f});
                    v2f aq = pk_fma(wrec[1], hr[1], (v2f){0.f, 0.f});
                    #pragma unroll
                    for (int j = 2; j < 8; j += 2) {
                        ap = pk_fma(wrec[j],     hr[j],     ap);
                        aq = pk_fma(wrec[j + 1], hr[j + 1], aq);
                    }
                    ap = pk_fma(win[0], (v2f){q0.x, q0.y}, ap);
                    aq = pk_fma(win[1], (v2f){q0.z, q0.w}, aq);
                    const v4f q2 = hq[2];
                    const v4f q3 = hq[3];
                    ap = pk_fma(win[2], (v2f){q1.x, q1.y}, ap);
                    aq = pk_fma(win[3], (v2f){q1.z, q1.w}, aq);
                    ap = pk_fma(win[4], (v2f){q2.x, q2.y}, ap);
                    aq = pk_fma(win[5], (v2f){q2.z, q2.w}, aq);
                    ap = pk_fma(win[6], (v2f){q3.x, q3.y}, ap);
                    aq = pk_fma(win[7], (v2f){q3.z, q3.w}, aq);
                    const v2f s = ap + aq;
                    const float g = s.x + s.y;
                    const float a = __builtin_fmaf(vAa,
                        __builtin_amdgcn_rcpf(1.0f + __builtin_amdgcn_exp2f(g)), vBc);
                    const float gi = qperm<0x00>(a);
                    const float gf = qperm<0x55>(a);
                    const float gg = qperm<0xAA>(a);
                    const float go = qperm<0xFF>(a);
                    cst = __builtin_fmaf(gf, cst, gi * gg);
                    const float tc = __builtin_fmaf(2.0f,
                        __builtin_amdgcn_rcpf(1.0f +
                            __builtin_amdgcn_exp2f(-2.0f * LOG2E * cst)), -1.0f);
                    h2v = go * tc;                  // quad-replicated
                    shh2[bw][r] = h2v;
                    // read h2 row back ONCE for next step's wh2 dot
                    const v4f* const h2q = (const v4f*)&shh2[bw][0];
                    #pragma unroll
                    for (int j = 0; j < 4; ++j) {
                        const v4f q = h2q[j];
                        hr[2 * j]     = (v2f){q.x, q.y};
                        hr[2 * j + 1] = (v2f){q.z, q.w};
                    }
                    ssum += __builtin_amdgcn_exp2f(LOG2E * h2v);
                }
            }
        }
    }

    if (isL2) {
        // s[b,k] = exp(h2[T-1,k]) / sum_t exp(h2[t,k]); h2v replicated per quad.
        const float sv = __builtin_amdgcn_exp2f(LOG2E * h2v) / ssum;

        float ssb[H_DIM];
        #pragma unroll
        for (int k = 0; k < H_DIM; ++k) ssb[k] = bcast_lane(sv, 4 * k);

        // Dense head 16 -> 8 -> 8 -> 3 + softmax (one-time epilogue).
        const int r8 = lane & 7;
        float acc1 = bd1[r8];
        #pragma unroll
        for (int k = 0; k < H_DIM; ++k)
            acc1 = __builtin_fmaf(Wd1[r8 * H_DIM + k], ssb[k], acc1);

        float d1s[8];
        #pragma unroll
        for (int j = 0; j < 8; ++j) d1s[j] = bcast_lane(acc1, j);

        float acc2 = bd2[r8];
        #pragma unroll
        for (int k = 0; k < 8; ++k)
            acc2 = __builtin_fmaf(Wd2[r8 * 8 + k], d1s[k], acc2);

        float d2s[8];
        #pragma unroll
        for (int j = 0; j < 8; ++j) d2s[j] = bcast_lane(acc2, j);

        float lg = 0.f;
        if (lane < 3) {
            lg = bd3[lane];
            #pragma unroll
            for (int k = 0; k < 8; ++k)
                lg = __builtin_fmaf(Wd3[lane * 8 + k], d2s[k], lg);
        }
        const float l0 = bcast_lane(lg, 0);
        const float l1 = bcast_lane(lg, 1);
        const float l2 = bcast_lane(lg, 2);
        const float mx = fmaxf(l0, fmaxf(l1, l2));
        const float e0 = __builtin_amdgcn_exp2f(LOG2E * (l0 - mx));
        const float e1 = __builtin_amdgcn_exp2f(LOG2E * (l1 - mx));
        const float e2 = __builtin_amdgcn_exp2f(LOG2E * (l2 - mx));
        const float inv = 1.0f / (e0 + e1 + e2);
        if (lane < 3) {
            const float ev = (lane == 0) ? e0 : ((lane == 1) ? e1 : e2);
            out[b * 3 + lane] = ev * inv;
        }
    }
}

extern "C" void kernel_launch(void* const* d_in, const int* in_sizes, int n_in,
                              void* d_out, int out_size, void* d_ws, size_t ws_size,
                              hipStream_t stream) {
    (void)in_sizes; (void)n_in; (void)out_size; (void)d_ws; (void)ws_size;
    const float* x    = (const float*)d_in[0];
    const float* Wih1 = (const float*)d_in[1];
    const float* Whh1 = (const float*)d_in[2];
    const float* bih1 = (const float*)d_in[3];
    const float* bhh1 = (const float*)d_in[4];
    const float* Wih2 = (const float*)d_in[5];
    const float* Whh2 = (const float*)d_in[6];
    const float* bih2 = (const float*)d_in[7];
    const float* bhh2 = (const float*)d_in[8];
    const float* Wd1  = (const float*)d_in[9];
    const float* bd1  = (const float*)d_in[10];
    const float* Wd2  = (const float*)d_in[11];
    const float* bd2  = (const float*)d_in[12];
    const float* Wd3  = (const float*)d_in[13];
    const float* bd3  = (const float*)d_in[14];

    lstm2_head<<<dim3(4096 / 2), dim3(256), 0, stream>>>(
        x, Wih1, Whh1, bih1, bhh1, Wih2, Whh2, bih2, bhh2,
        Wd1, bd1, Wd2, bd2, Wd3, bd3, (float*)d_out);
}

// Round 4
// 495.196 us; speedup vs baseline: 1.7199x; 1.7199x over previous
//
#include <hip/hip_runtime.h>

#define T_STEPS 512
#define IN_DIM 11
#define ROW_PAD 12                  // x row padded to 12 floats in LDS
#define H_DIM 16
#define ROW_F (T_STEPS * IN_DIM)    // 5632 floats per batch row
#define CHUNK_T 16                  // t-steps per chunk (pipeline granule)
#define CHUNK_F (CHUNK_T * IN_DIM)  // 176 source floats per chunk
#define N_CHUNK (T_STEPS / CHUNK_T)
#define LOG2E 1.44269504088896340736f

typedef float v2f __attribute__((ext_vector_type(2)));
typedef float v4f __attribute__((ext_vector_type(4)));

// Packed fp32 FMA (v_pk_fma_f32): 2 MACs/instr, full rate.
__device__ __forceinline__ v2f pk_fma(v2f a, v2f b, v2f c) {
    v2f d;
    asm("v_pk_fma_f32 %0, %1, %2, %3" : "=v"(d) : "v"(a), "v"(b), "v"(c));
    return d;
}

// DPP quad_perm broadcast within each group of 4 lanes.
template<int CTRL>
__device__ __forceinline__ float qperm(float v) {
    return __builtin_bit_cast(float,
        __builtin_amdgcn_update_dpp(0, __builtin_bit_cast(int, v),
                                    CTRL, 0xf, 0xf, true));
}

__device__ __forceinline__ float bcast_lane(float v, int l) {
    return __builtin_bit_cast(float,
        __builtin_amdgcn_readlane(__builtin_bit_cast(int, v), l));
}

// LAYER-PIPELINED 2-layer LSTM.
// Block = 256 threads = 4 waves = 2 batches x {L1-wave, L2-wave}.
//   wave 0,1: layer-1 for batch bw=0,1  (consumes x, produces h1 ring)
//   wave 2,3: layer-2 for batch bw=0,1  (consumes h1 ring, one chunk behind)
// ROUND-2 POST-MORTEM: __launch_bounds__(256,8) capped the unified reg
// budget at 64/lane -> ~90 needed -> scratch spill (FETCH 1.57 GB, WRITE
// 1.19 GB/dispatch, 765 us). (256,4) gives a 128 budget: whole working set
// (32 weight VGPRs + 16 hr + temps) fits in ARCH VGPRs - no spill, no
// AGPR round-trips on the recurrent chain - while keeping 8192 waves.
// Per-chunk __syncthreads() (33 total) publishes the double-buffered h1 ring.
// Lane = 4*r + gate (i,f,g,o quads); weights M-scaled in pinned VGPRs.
__global__ __launch_bounds__(256, 4) void lstm2_head(
    const float* __restrict__ x,
    const float* __restrict__ Wih1, const float* __restrict__ Whh1,
    const float* __restrict__ bih1, const float* __restrict__ bhh1,
    const float* __restrict__ Wih2, const float* __restrict__ Whh2,
    const float* __restrict__ bih2, const float* __restrict__ bhh2,
    const float* __restrict__ Wd1, const float* __restrict__ bd1,
    const float* __restrict__ Wd2, const float* __restrict__ bd2,
    const float* __restrict__ Wd3, const float* __restrict__ bd3,
    float* __restrict__ out)
{
    __shared__ alignas(16) float xlds[2][212];                 // [bw][padded chunk]
    __shared__ alignas(16) float ring[2][2][CHUNK_T][H_DIM];   // [bw][buf][t2][r]
    __shared__ alignas(16) float shh2[2][H_DIM];               // [bw][r] h2 bcast slab

    const int lane = threadIdx.x & 63;
    const int wid = __builtin_amdgcn_readfirstlane((int)(threadIdx.x >> 6));
    const int isL2 = wid >> 1;          // 0: layer-1 wave, 1: layer-2 wave
    const int bw   = wid & 1;           // batch slot within block
    const int b    = blockIdx.x * 2 + bw;

    const int r   = lane >> 2;          // hidden index 0..15
    const int gt  = lane & 3;           // 0:i 1:f 2:g(tanh) 3:o
    const int row = gt * H_DIM + r;     // row in packed 4H weights

    const bool is_t = (gt == 2);
    const float M   = is_t ? (-2.0f * LOG2E) : (-LOG2E);
    const float vAa = is_t ? 2.0f : 1.0f;
    const float vBc = is_t ? -1.0f : 0.0f;

    // ---- per-wave weights (M-scaled), packed in v2f, pinned ----
    // L1: win = Wih1 (6 pairs used, 11 inputs + zero pad), wrec = Whh1
    // L2: win = Wih2, wrec = Whh2
    v2f win[8], wrec[8];
    float bb;
    if (!isL2) {
        #pragma unroll
        for (int j = 0; j < 5; ++j)
            win[j] = (v2f){M * Wih1[row * IN_DIM + 2 * j],
                           M * Wih1[row * IN_DIM + 2 * j + 1]};
        win[5] = (v2f){M * Wih1[row * IN_DIM + 10], 0.0f};   // pad weight = 0
        win[6] = (v2f){0.f, 0.f};
        win[7] = (v2f){0.f, 0.f};
        #pragma unroll
        for (int j = 0; j < 8; ++j)
            wrec[j] = (v2f){M * Whh1[row * H_DIM + 2 * j],
                            M * Whh1[row * H_DIM + 2 * j + 1]};
        bb = M * (bih1[row] + bhh1[row]);
    } else {
        #pragma unroll
        for (int j = 0; j < 8; ++j) {
            win[j]  = (v2f){M * Wih2[row * H_DIM + 2 * j],
                            M * Wih2[row * H_DIM + 2 * j + 1]};
            wrec[j] = (v2f){M * Whh2[row * H_DIM + 2 * j],
                            M * Whh2[row * H_DIM + 2 * j + 1]};
        }
        bb = M * (bih2[row] + bhh2[row]);
    }
    #pragma unroll
    for (int j = 0; j < 8; ++j) {
        asm volatile("" : "+v"(win[j]));
        asm volatile("" : "+v"(wrec[j]));
    }

    // x staging offsets (L1 waves): source float f -> slot (f/11)*12 + f%11
    const int f1i = lane, f2i = lane + 64, f3i = lane + 128;
    const int p1 = (f1i / IN_DIM) * ROW_PAD + (f1i % IN_DIM);
    const int p2 = (f2i / IN_DIM) * ROW_PAD + (f2i % IN_DIM);
    const int p3 = (f3i / IN_DIM) * ROW_PAD + (f3i % IN_DIM);
    const float* __restrict__ xb = x + (size_t)b * ROW_F;

    float gl0 = 0.f, gl1 = 0.f, gl2 = 0.f;
    if (!isL2) {
        if (lane < 16) xlds[bw][lane * ROW_PAD + IN_DIM] = 0.0f;  // zero pad slots
        gl0 = xb[f1i];                      // prologue: global-load chunk 0
        gl1 = xb[f2i];
        gl2 = xb[min(f3i, ROW_F - 1)];
    }

    float cst = 0.f, ssum = 0.f, h2v = 0.f;
    v2f hr[8];                              // recurrent h pairs (own layer)
    #pragma unroll
    for (int j = 0; j < 8; ++j) hr[j] = (v2f){0.f, 0.f};

    for (int ck = 0; ck <= N_CHUNK; ++ck) {
        __syncthreads();                    // publish ring chunk ck-1 to L2 waves

        if (!isL2) {
            // -------- layer-1 producer: chunk ck -> ring[ck&1] --------
            if (ck < N_CHUNK) {
                float* const xbuf = &xlds[bw][0];
                xbuf[p1] = gl0;
                xbuf[p2] = gl1;
                xbuf[p3] = gl2;
                if (ck + 1 < N_CHUNK) {
                    const int base = (ck + 1) * CHUNK_F;
                    gl0 = xb[base + f1i];
                    gl1 = xb[base + f2i];
                    gl2 = xb[min(base + f3i, ROW_F - 1)];
                }
                float (* const rg)[H_DIM] = ring[bw][ck & 1];
                #pragma unroll
                for (int t2 = 0; t2 < CHUNK_T; ++t2) {
                    const v2f* const xr = (const v2f*)(xbuf + t2 * ROW_PAD);
                    v2f ap = pk_fma(win[0], xr[0], (v2f){bb, 0.f});
                    v2f aq = pk_fma(win[1], xr[1], (v2f){0.f, 0.f});
                    ap = pk_fma(win[2], xr[2], ap);
                    aq = pk_fma(win[3], xr[3], aq);
                    ap = pk_fma(win[4], xr[4], ap);
                    aq = pk_fma(win[5], xr[5], aq);
                    #pragma unroll
                    for (int j = 0; j < 8; j += 2) {
                        ap = pk_fma(wrec[j],     hr[j],     ap);
                        aq = pk_fma(wrec[j + 1], hr[j + 1], aq);
                    }
                    const v2f s = ap + aq;
                    const float g = s.x + s.y;
                    const float a = __builtin_fmaf(vAa,
                        __builtin_amdgcn_rcpf(1.0f + __builtin_amdgcn_exp2f(g)), vBc);
                    const float gi = qperm<0x00>(a);
                    const float gf = qperm<0x55>(a);
                    const float gg = qperm<0xAA>(a);
                    const float go = qperm<0xFF>(a);
                    cst = __builtin_fmaf(gf, cst, gi * gg);
                    const float tc = __builtin_fmaf(2.0f,
                        __builtin_amdgcn_rcpf(1.0f +
                            __builtin_amdgcn_exp2f(-2.0f * LOG2E * cst)), -1.0f);
                    rg[t2][r] = go * tc;            // quad-replicated write
                    // read row back ONCE for next step's recurrent dot
                    const v4f* const hq = (const v4f*)&rg[t2][0];
                    #pragma unroll
                    for (int j = 0; j < 4; ++j) {
                        const v4f q = hq[j];
                        hr[2 * j]     = (v2f){q.x, q.y};
                        hr[2 * j + 1] = (v2f){q.z, q.w};
                    }
                }
            }
        } else {
            // -------- layer-2 consumer: chunk ck-1 <- ring[(ck-1)&1] --------
            if (ck >= 1) {
                float (* const rg)[H_DIM] = ring[bw][(ck - 1) & 1];
                #pragma unroll
                for (int t2 = 0; t2 < CHUNK_T; ++t2) {
                    const v4f* const hq = (const v4f*)&rg[t2][0];
                    // stage first half of h1 row early (overlap with wh2 dot)
                    const v4f q0 = hq[0];
                    const v4f q1 = hq[1];
                    v2f ap = pk_fma(wrec[0], hr[0], (v2f){bb, 0.f});
                    v2f aq = pk_fma(wrec[1], hr[1], (v2f){0.f, 0.f});
                    #pragma unroll
                    for (int j = 2; j < 8; j += 2) {
                        ap = pk_fma(wrec[j],     hr[j],     ap);
                        aq = pk_fma(wrec[j + 1], hr[j + 1], aq);
                    }
                    ap = pk_fma(win[0], (v2f){q0.x, q0.y}, ap);
                    aq = pk_fma(win[1], (v2f){q0.z, q0.w}, aq);
                    const v4f q2 = hq[2];
                    const v4f q3 = hq[3];
                    ap = pk_fma(win[2], (v2f){q1.x, q1.y}, ap);
                    aq = pk_fma(win[3], (v2f){q1.z, q1.w}, aq);
                    ap = pk_fma(win[4], (v2f){q2.x, q2.y}, ap);
                    aq = pk_fma(win[5], (v2f){q2.z, q2.w}, aq);
                    ap = pk_fma(win[6], (v2f){q3.x, q3.y}, ap);
                    aq = pk_fma(win[7], (v2f){q3.z, q3.w}, aq);
                    const v2f s = ap + aq;
                    const float g = s.x + s.y;
                    const float a = __builtin_fmaf(vAa,
                        __builtin_amdgcn_rcpf(1.0f + __builtin_amdgcn_exp2f(g)), vBc);
                    const float gi = qperm<0x00>(a);
                    const float gf = qperm<0x55>(a);
                    const float gg = qperm<0xAA>(a);
                    const float go = qperm<0xFF>(a);
                    cst = __builtin_fmaf(gf, cst, gi * gg);
                    const float tc = __builtin_fmaf(2.0f,
                        __builtin_amdgcn_rcpf(1.0f +
                            __builtin_amdgcn_exp2f(-2.0f * LOG2E * cst)), -1.0f);
                    h2v = go * tc;                  // quad-replicated
                    shh2[bw][r] = h2v;
                    // read h2 row back ONCE for next step's wh2 dot
                    const v4f* const h2q = (const v4f*)&shh2[bw][0];
                    #pragma unroll
                    for (int j = 0; j < 4; ++j) {
                        const v4f q = h2q[j];
                        hr[2 * j]     = (v2f){q.x, q.y};
                        hr[2 * j + 1] = (v2f){q.z, q.w};
                    }
                    ssum += __builtin_amdgcn_exp2f(LOG2E * h2v);
                }
            }
        }
    }

    if (isL2) {
        // s[b,k] = exp(h2[T-1,k]) / sum_t exp(h2[t,k]); h2v replicated per quad.
        const float sv = __builtin_amdgcn_exp2f(LOG2E * h2v) / ssum;

        float ssb[H_DIM];
        #pragma unroll
        for (int k = 0; k < H_DIM; ++k) ssb[k] = bcast_lane(sv, 4 * k);

        // Dense head 16 -> 8 -> 8 -> 3 + softmax (one-time epilogue).
        const int r8 = lane & 7;
        float acc1 = bd1[r8];
        #pragma unroll
        for (int k = 0; k < H_DIM; ++k)
            acc1 = __builtin_fmaf(Wd1[r8 * H_DIM + k], ssb[k], acc1);

        float d1s[8];
        #pragma unroll
        for (int j = 0; j < 8; ++j) d1s[j] = bcast_lane(acc1, j);

        float acc2 = bd2[r8];
        #pragma unroll
        for (int k = 0; k < 8; ++k)
            acc2 = __builtin_fmaf(Wd2[r8 * 8 + k], d1s[k], acc2);

        float d2s[8];
        #pragma unroll
        for (int j = 0; j < 8; ++j) d2s[j] = bcast_lane(acc2, j);

        float lg = 0.f;
        if (lane < 3) {
            lg = bd3[lane];
            #pragma unroll
            for (int k = 0; k < 8; ++k)
                lg = __builtin_fmaf(Wd3[lane * 8 + k], d2s[k], lg);
        }
        const float l0 = bcast_lane(lg, 0);
        const float l1 = bcast_lane(lg, 1);
        const float l2 = bcast_lane(lg, 2);
        const float mx = fmaxf(l0, fmaxf(l1, l2));
        const float e0 = __builtin_amdgcn_exp2f(LOG2E * (l0 - mx));
        const float e1 = __builtin_amdgcn_exp2f(LOG2E * (l1 - mx));
        const float e2 = __builtin_amdgcn_exp2f(LOG2E * (l2 - mx));
        const float inv = 1.0f / (e0 + e1 + e2);
        if (lane < 3) {
            const float ev = (lane == 0) ? e0 : ((lane == 1) ? e1 : e2);
            out[b * 3 + lane] = ev * inv;
        }
    }
}

extern "C" void kernel_launch(void* const* d_in, const int* in_sizes, int n_in,
                              void* d_out, int out_size, void* d_ws, size_t ws_size,
                              hipStream_t stream) {
    (void)in_sizes; (void)n_in; (void)out_size; (void)d_ws; (void)ws_size;
    const float* x    = (const float*)d_in[0];
    const float* Wih1 = (const float*)d_in[1];
    const float* Whh1 = (const float*)d_in[2];
    const float* bih1 = (const float*)d_in[3];
    const float* bhh1 = (const float*)d_in[4];
    const float* Wih2 = (const float*)d_in[5];
    const float* Whh2 = (const float*)d_in[6];
    const float* bih2 = (const float*)d_in[7];
    const float* bhh2 = (const float*)d_in[8];
    const float* Wd1  = (const float*)d_in[9];
    const float* bd1  = (const float*)d_in[10];
    const float* Wd2  = (const float*)d_in[11];
    const float* bd2  = (const float*)d_in[12];
    const float* Wd3  = (const float*)d_in[13];
    const float* bd3  = (const float*)d_in[14];

    lstm2_head<<<dim3(4096 / 2), dim3(256), 0, stream>>>(
        x, Wih1, Whh1, bih1, bhh1, Wih2, Whh2, bih2, bhh2,
        Wd1, bd1, Wd2, bd2, Wd3, bd3, (float*)d_out);
}